// Round 1
// baseline (1765.841 us; speedup 1.0000x reference)
//
#include <hip/hip_runtime.h>
#include <math.h>

#define D_MODEL   1024
#define NUM_HEADS 16
#define DEPTH     64
#define S_LEN     2048
#define BATCH     2

// ---------------------------------------------------------------------------
// K1/K4: C = X[M,1024] @ W[1024,1024] + bias
// mode 0: scatter to head-split [B,H,S,DEPTH]; mode 1: plain [M,1024]
// 64x64 tile, BK=16, 256 threads, 4x4 per thread, fp32.
// ---------------------------------------------------------------------------
__global__ __launch_bounds__(256) void gemm_proj(const float* __restrict__ X,
                                                 const float* __restrict__ W,
                                                 const float* __restrict__ bias,
                                                 float* __restrict__ out,
                                                 int mode)
{
    const int K = 1024, N = 1024;
    __shared__ float As[16][64 + 1];   // [k][m], scalar stores
    __shared__ float Bs[16][64 + 4];   // [k][n], float4 stores (stride 68 -> 16B aligned)

    const int tid = threadIdx.x;
    const int tx = tid % 16, ty = tid / 16;
    const int bm = blockIdx.x * 64;
    const int bn = blockIdx.y * 64;

    float acc[4][4] = {};

    for (int k0 = 0; k0 < K; k0 += 16) {
        // A tile: 64 rows x 16 cols
        {
            int r  = tid / 4;
            int c4 = (tid % 4) * 4;
            const float4 av = *(const float4*)&X[(size_t)(bm + r) * K + k0 + c4];
            As[c4 + 0][r] = av.x;
            As[c4 + 1][r] = av.y;
            As[c4 + 2][r] = av.z;
            As[c4 + 3][r] = av.w;
        }
        // B tile: 16 rows x 64 cols
        {
            int r  = tid / 16;
            int c4 = (tid % 16) * 4;
            *(float4*)&Bs[r][c4] = *(const float4*)&W[(size_t)(k0 + r) * N + bn + c4];
        }
        __syncthreads();
#pragma unroll
        for (int kk = 0; kk < 16; ++kk) {
            float a[4], b[4];
#pragma unroll
            for (int i = 0; i < 4; ++i) a[i] = As[kk][ty * 4 + i];
#pragma unroll
            for (int j = 0; j < 4; ++j) b[j] = Bs[kk][tx * 4 + j];
#pragma unroll
            for (int i = 0; i < 4; ++i)
#pragma unroll
                for (int j = 0; j < 4; ++j) acc[i][j] += a[i] * b[j];
        }
        __syncthreads();
    }

#pragma unroll
    for (int i = 0; i < 4; ++i) {
        int m = bm + ty * 4 + i;
        int b_idx = m / S_LEN, s_idx = m % S_LEN;
#pragma unroll
        for (int j = 0; j < 4; ++j) {
            int n = bn + tx * 4 + j;
            float val = acc[i][j] + bias[n];
            if (mode == 0) {
                int h = n / DEPTH, dc = n % DEPTH;
                out[(((size_t)b_idx * NUM_HEADS + h) * S_LEN + s_idx) * DEPTH + dc] = val;
            } else {
                out[(size_t)m * N + n] = val;
            }
        }
    }
}

// ---------------------------------------------------------------------------
// K2a: logits[bh][i][j] = scale * dot(Qh[bh][i], Kh[bh][j]); K=64 fully in LDS
// ---------------------------------------------------------------------------
__global__ __launch_bounds__(256) void scores_kernel(const float* __restrict__ Qh,
                                                     const float* __restrict__ Kh,
                                                     float* __restrict__ attn)
{
    const int S = S_LEN, D = DEPTH;
    const float scale = 0.125f;  // 1/sqrt(64)
    const int bh = blockIdx.z;
    const float* Q  = Qh + (size_t)bh * S * D;
    const float* Kp = Kh + (size_t)bh * S * D;
    float* C = attn + (size_t)bh * S * S;

    __shared__ float Qs[64][64 + 1];  // [k][m]
    __shared__ float Ks[64][64 + 1];  // [k][n]

    const int tid = threadIdx.x;
    const int tx = tid % 16, ty = tid / 16;
    const int bm = blockIdx.x * 64;
    const int bn = blockIdx.y * 64;

    for (int r0 = 0; r0 < 64; r0 += 16) {
        int r  = r0 + tid / 16;
        int c4 = (tid % 16) * 4;
        const float4 qv = *(const float4*)&Q[(size_t)(bm + r) * D + c4];
        Qs[c4 + 0][r] = qv.x; Qs[c4 + 1][r] = qv.y;
        Qs[c4 + 2][r] = qv.z; Qs[c4 + 3][r] = qv.w;
        const float4 kv = *(const float4*)&Kp[(size_t)(bn + r) * D + c4];
        Ks[c4 + 0][r] = kv.x; Ks[c4 + 1][r] = kv.y;
        Ks[c4 + 2][r] = kv.z; Ks[c4 + 3][r] = kv.w;
    }
    __syncthreads();

    float acc[4][4] = {};
#pragma unroll 16
    for (int kk = 0; kk < 64; ++kk) {
        float a[4], b[4];
#pragma unroll
        for (int i = 0; i < 4; ++i) a[i] = Qs[kk][ty * 4 + i];
#pragma unroll
        for (int j = 0; j < 4; ++j) b[j] = Ks[kk][tx * 4 + j];
#pragma unroll
        for (int i = 0; i < 4; ++i)
#pragma unroll
            for (int j = 0; j < 4; ++j) acc[i][j] += a[i] * b[j];
    }

#pragma unroll
    for (int i = 0; i < 4; ++i) {
        int m = bm + ty * 4 + i;
#pragma unroll
        for (int j = 0; j < 4; ++j) {
            int n = bn + tx * 4 + j;
            C[(size_t)m * S + n] = acc[i][j] * scale;
        }
    }
}

// ---------------------------------------------------------------------------
// K2b: rowwise softmax in place; one block (256 thr) per row of 2048
// ---------------------------------------------------------------------------
__global__ __launch_bounds__(256) void softmax_kernel(float* __restrict__ attn)
{
    const size_t row = blockIdx.x;
    float* p = attn + row * (size_t)S_LEN;
    const int tid = threadIdx.x;

    float4 v0 = ((const float4*)p)[tid];
    float4 v1 = ((const float4*)p)[tid + 256];

    float m = fmaxf(fmaxf(fmaxf(v0.x, v0.y), fmaxf(v0.z, v0.w)),
                    fmaxf(fmaxf(v1.x, v1.y), fmaxf(v1.z, v1.w)));
#pragma unroll
    for (int off = 32; off > 0; off >>= 1) m = fmaxf(m, __shfl_xor(m, off));

    __shared__ float redm[4];
    __shared__ float reds[4];
    const int wave = tid >> 6, lane = tid & 63;
    if (lane == 0) redm[wave] = m;
    __syncthreads();
    m = fmaxf(fmaxf(redm[0], redm[1]), fmaxf(redm[2], redm[3]));

    v0.x = __expf(v0.x - m); v0.y = __expf(v0.y - m);
    v0.z = __expf(v0.z - m); v0.w = __expf(v0.w - m);
    v1.x = __expf(v1.x - m); v1.y = __expf(v1.y - m);
    v1.z = __expf(v1.z - m); v1.w = __expf(v1.w - m);

    float s = v0.x + v0.y + v0.z + v0.w + v1.x + v1.y + v1.z + v1.w;
#pragma unroll
    for (int off = 32; off > 0; off >>= 1) s += __shfl_xor(s, off);
    if (lane == 0) reds[wave] = s;
    __syncthreads();
    s = reds[0] + reds[1] + reds[2] + reds[3];

    const float inv = 1.0f / s;
    v0.x *= inv; v0.y *= inv; v0.z *= inv; v0.w *= inv;
    v1.x *= inv; v1.y *= inv; v1.z *= inv; v1.w *= inv;
    ((float4*)p)[tid]       = v0;
    ((float4*)p)[tid + 256] = v1;
}

// ---------------------------------------------------------------------------
// K3: ctx[bh] = attn[bh] (2048x2048) @ Vh[bh] (2048x64), scatter to [B,S,D_MODEL]
// ---------------------------------------------------------------------------
__global__ __launch_bounds__(256) void ctx_kernel(const float* __restrict__ attn,
                                                  const float* __restrict__ Vh,
                                                  float* __restrict__ ctx)
{
    const int S = S_LEN, D = DEPTH;
    const int bh = blockIdx.y;
    const int b = bh / NUM_HEADS, h = bh % NUM_HEADS;
    const float* A = attn + (size_t)bh * S * S;
    const float* V = Vh + (size_t)bh * S * D;
    const int bm = blockIdx.x * 64;

    __shared__ float As[16][64 + 1];  // [k][m]
    __shared__ float Vs[16][64 + 4];  // [k][n], float4 stores

    const int tid = threadIdx.x;
    const int tx = tid % 16, ty = tid / 16;

    float acc[4][4] = {};

    for (int k0 = 0; k0 < S; k0 += 16) {
        {
            int r  = tid / 4;
            int c4 = (tid % 4) * 4;
            const float4 av = *(const float4*)&A[(size_t)(bm + r) * S + k0 + c4];
            As[c4 + 0][r] = av.x; As[c4 + 1][r] = av.y;
            As[c4 + 2][r] = av.z; As[c4 + 3][r] = av.w;
        }
        {
            int r  = tid / 16;
            int c4 = (tid % 16) * 4;
            *(float4*)&Vs[r][c4] = *(const float4*)&V[(size_t)(k0 + r) * D + c4];
        }
        __syncthreads();
#pragma unroll
        for (int kk = 0; kk < 16; ++kk) {
            float a[4], b[4];
#pragma unroll
            for (int i = 0; i < 4; ++i) a[i] = As[kk][ty * 4 + i];
#pragma unroll
            for (int j = 0; j < 4; ++j) b[j] = Vs[kk][tx * 4 + j];
#pragma unroll
            for (int i = 0; i < 4; ++i)
#pragma unroll
                for (int j = 0; j < 4; ++j) acc[i][j] += a[i] * b[j];
        }
        __syncthreads();
    }

#pragma unroll
    for (int i = 0; i < 4; ++i) {
        int s_idx = bm + ty * 4 + i;
#pragma unroll
        for (int j = 0; j < 4; ++j) {
            int dc = tx * 4 + j;
            ctx[((size_t)b * S + s_idx) * D_MODEL + h * DEPTH + dc] = acc[i][j];
        }
    }
}

// ---------------------------------------------------------------------------
extern "C" void kernel_launch(void* const* d_in, const int* in_sizes, int n_in,
                              void* d_out, int out_size, void* d_ws, size_t ws_size,
                              hipStream_t stream)
{
    const float* q  = (const float*)d_in[0];
    const float* k  = (const float*)d_in[1];
    const float* v  = (const float*)d_in[2];
    const float* wq = (const float*)d_in[3];
    const float* bq = (const float*)d_in[4];
    const float* wk = (const float*)d_in[5];
    const float* bk = (const float*)d_in[6];
    const float* wv = (const float*)d_in[7];
    const float* bv = (const float*)d_in[8];
    const float* wo = (const float*)d_in[9];
    const float* bo = (const float*)d_in[10];

    float* out  = (float*)d_out;                                    // [2,2048,1024]
    float* attn = out + (size_t)BATCH * S_LEN * D_MODEL;            // [2,16,2048,2048]

    const size_t headElems = (size_t)BATCH * NUM_HEADS * S_LEN * DEPTH;  // 4M floats
    float* Qh  = (float*)d_ws;
    float* Kh  = Qh + headElems;
    float* Vh  = Kh + headElems;
    float* ctx = Qh;  // Qh dead after scores_kernel

    dim3 blk(256);

    // QKV projections with head-split epilogue
    gemm_proj<<<dim3(64, 16), blk, 0, stream>>>(q, wq, bq, Qh, 0);
    gemm_proj<<<dim3(64, 16), blk, 0, stream>>>(k, wk, bk, Kh, 0);
    gemm_proj<<<dim3(64, 16), blk, 0, stream>>>(v, wv, bv, Vh, 0);

    // logits -> attn (raw scaled), then softmax in place
    scores_kernel<<<dim3(32, 32, BATCH * NUM_HEADS), blk, 0, stream>>>(Qh, Kh, attn);
    softmax_kernel<<<dim3(BATCH * NUM_HEADS * S_LEN), blk, 0, stream>>>(attn);

    // ctx = attn @ V, scattered back to [B,S,D_MODEL]
    ctx_kernel<<<dim3(32, BATCH * NUM_HEADS), blk, 0, stream>>>(attn, Vh, ctx);

    // output projection
    gemm_proj<<<dim3(64, 16), blk, 0, stream>>>(ctx, wo, bo, out, 1);
}